// Round 1
// baseline (23201.662 us; speedup 1.0000x reference)
//
#include <hip/hip_runtime.h>
#include <math.h>

#define VOCAB 16000
#define EMBED 256
#define HIDDEN 512
#define BATCH 8
#define SEQ 2048

// ---------------- generic 32x32 tiled transpose: dst[N x M] = src[M x N]^T ----
__global__ void k_transpose(const float* __restrict__ src, float* __restrict__ dst,
                            int M, int N) {
  __shared__ float tile[32][33];
  int bx = blockIdx.x * 32, by = blockIdx.y * 32;
  int tx = threadIdx.x, ty = threadIdx.y;
  for (int r = ty; r < 32; r += 8) {
    int row = by + r, col = bx + tx;
    if (row < M && col < N) tile[r][tx] = src[row * N + col];
  }
  __syncthreads();
  for (int r = ty; r < 32; r += 8) {
    int row = bx + r, col = by + tx;  // dst is N x M
    if (row < N && col < M) dst[row * M + col] = tile[tx][r];
  }
}

// ---------------- xp[m][h] = emb[x[m]] . W_ih[h,:] + b_ih[h] + b_hh[h] --------
// grid = 16384/16 blocks, 512 threads. Wt_ih is [EMBED][HIDDEN] (transposed).
__global__ void k_xproj(const int* __restrict__ x, const float* __restrict__ emb,
                        const float* __restrict__ Wt_ih, const float* __restrict__ b_ih,
                        const float* __restrict__ b_hh, float* __restrict__ xp) {
  __shared__ float a[16][EMBED];
  __shared__ int idx[16];
  const int tid = threadIdx.x;
  const int m0 = blockIdx.x * 16;
  if (tid < 16) idx[tid] = x[m0 + tid];
  __syncthreads();
#pragma unroll
  for (int c = 0; c < 8; ++c) {          // 16*256 = 4096 = 8 * 512
    int f = c * 512 + tid;
    int r = f >> 8, e = f & 255;
    a[r][e] = emb[(size_t)idx[r] * EMBED + e];
  }
  __syncthreads();
  const float bias = b_ih[tid] + b_hh[tid];
  float acc[16];
#pragma unroll
  for (int r = 0; r < 16; ++r) acc[r] = 0.f;
  for (int e = 0; e < EMBED; e += 4) {
    float w0 = Wt_ih[(e + 0) * HIDDEN + tid];
    float w1 = Wt_ih[(e + 1) * HIDDEN + tid];
    float w2 = Wt_ih[(e + 2) * HIDDEN + tid];
    float w3 = Wt_ih[(e + 3) * HIDDEN + tid];
#pragma unroll
    for (int r = 0; r < 16; ++r) {
      float4 av = *(const float4*)&a[r][e];
      acc[r] += av.x * w0 + av.y * w1 + av.z * w2 + av.w * w3;
    }
  }
#pragma unroll
  for (int r = 0; r < 16; ++r)
    xp[(size_t)(m0 + r) * HIDDEN + tid] = acc[r] + bias;
}

// ---------------- recurrence: one block per batch chain ----------------------
// buf holds xp on entry; overwritten in place with output_seq (h_t).
// Wt_hh is [j][i] = W_hh[i][j] so lane i reads coalesced.
__global__ void k_rnn(const float* __restrict__ hidden0, const float* __restrict__ Wt_hh,
                      float* __restrict__ buf, float* __restrict__ out) {
  __shared__ float h[HIDDEN];
  const int i = threadIdx.x;
  const int b = blockIdx.x;
  h[i] = hidden0[b * HIDDEN + i];
  __syncthreads();
  float hn = 0.f;
  for (int t = 0; t < SEQ; ++t) {
    float a0 = 0.f, a1 = 0.f, a2 = 0.f, a3 = 0.f;
    for (int j = 0; j < HIDDEN; j += 8) {
      float4 h0 = *(const float4*)&h[j];
      float4 h1 = *(const float4*)&h[j + 4];
      const float* wp = Wt_hh + (size_t)j * HIDDEN + i;
      a0 += wp[0 * HIDDEN] * h0.x;
      a1 += wp[1 * HIDDEN] * h0.y;
      a2 += wp[2 * HIDDEN] * h0.z;
      a3 += wp[3 * HIDDEN] * h0.w;
      a0 += wp[4 * HIDDEN] * h1.x;
      a1 += wp[5 * HIDDEN] * h1.y;
      a2 += wp[6 * HIDDEN] * h1.z;
      a3 += wp[7 * HIDDEN] * h1.w;
    }
    size_t off = ((size_t)(b * SEQ + t)) * HIDDEN + i;
    float pre = (a0 + a1) + (a2 + a3) + buf[off];
    hn = tanhf(pre);
    __syncthreads();      // all reads of h done
    h[i] = hn;
    __syncthreads();      // new h visible
    buf[off] = hn;        // output_seq (aliases consumed xp element)
  }
  out[(size_t)BATCH * SEQ * VOCAB + b * HIDDEN + i] = hn;
}

// ---------------- logits: C[16384,16000] = hs[16384,512] @ Wout[16000,512]^T + b
// 128x128 C-tile, K-chunks of 16. 256 threads, 8x8 register micro-tile.
__global__ void k_logits(const float* __restrict__ hs, const float* __restrict__ Wout,
                         const float* __restrict__ bout, float* __restrict__ out) {
  __shared__ float at[16][132];
  __shared__ float bt[16][132];
  const int tid = threadIdx.x;
  const int n0 = blockIdx.x * 128;
  const int m0 = blockIdx.y * 128;
  const int tm = tid >> 4, tn = tid & 15;
  float acc[8][8];
#pragma unroll
  for (int r = 0; r < 8; ++r)
#pragma unroll
    for (int c = 0; c < 8; ++c) acc[r][c] = 0.f;

  for (int kc = 0; kc < HIDDEN; kc += 16) {
    float4 aA[2], bB[2];
#pragma unroll
    for (int i = 0; i < 2; ++i) {
      int q = tid + i * 256;            // 512 float4 total: 128 rows x 4
      int row = q >> 2, kq = q & 3;
      aA[i] = *(const float4*)&hs[(size_t)(m0 + row) * HIDDEN + kc + kq * 4];
      bB[i] = *(const float4*)&Wout[(size_t)(n0 + row) * HIDDEN + kc + kq * 4];
    }
    __syncthreads();
#pragma unroll
    for (int i = 0; i < 2; ++i) {
      int q = tid + i * 256;
      int row = q >> 2, kq = q & 3;
      at[kq * 4 + 0][row] = aA[i].x; at[kq * 4 + 1][row] = aA[i].y;
      at[kq * 4 + 2][row] = aA[i].z; at[kq * 4 + 3][row] = aA[i].w;
      bt[kq * 4 + 0][row] = bB[i].x; bt[kq * 4 + 1][row] = bB[i].y;
      bt[kq * 4 + 2][row] = bB[i].z; bt[kq * 4 + 3][row] = bB[i].w;
    }
    __syncthreads();
#pragma unroll
    for (int k = 0; k < 16; ++k) {
      float4 a0 = *(const float4*)&at[k][tm * 8];
      float4 a1 = *(const float4*)&at[k][tm * 8 + 4];
      float4 b0 = *(const float4*)&bt[k][tn * 8];
      float4 b1 = *(const float4*)&bt[k][tn * 8 + 4];
      float ar[8] = {a0.x, a0.y, a0.z, a0.w, a1.x, a1.y, a1.z, a1.w};
      float br[8] = {b0.x, b0.y, b0.z, b0.w, b1.x, b1.y, b1.z, b1.w};
#pragma unroll
      for (int r = 0; r < 8; ++r)
#pragma unroll
        for (int c = 0; c < 8; ++c) acc[r][c] += ar[r] * br[c];
    }
  }

  float bb[8];
#pragma unroll
  for (int c = 0; c < 8; ++c) bb[c] = bout[n0 + tn * 8 + c];
#pragma unroll
  for (int r = 0; r < 8; ++r) {
    size_t row = (size_t)(m0 + tm * 8 + r);
    float* p = out + row * VOCAB + n0 + tn * 8;
#pragma unroll
    for (int c = 0; c < 8; ++c) p[c] = acc[r][c] + bb[c];
  }
}

extern "C" void kernel_launch(void* const* d_in, const int* in_sizes, int n_in,
                              void* d_out, int out_size, void* d_ws, size_t ws_size,
                              hipStream_t stream) {
  const int*   x    = (const int*)d_in[0];
  const float* h0   = (const float*)d_in[1];
  const float* emb  = (const float*)d_in[2];
  const float* Wih  = (const float*)d_in[3];
  const float* Whh  = (const float*)d_in[4];
  const float* bih  = (const float*)d_in[5];
  const float* bhh  = (const float*)d_in[6];
  const float* Wout = (const float*)d_in[7];
  const float* bout = (const float*)d_in[8];
  float* out = (float*)d_out;

  char* ws = (char*)d_ws;
  float* buf  = (float*)(ws);                               // 16384*512*4 = 33.5 MB (xp, then outseq)
  float* WtIh = (float*)(ws + (size_t)33554432);            // 256*512*4
  float* WtHh = (float*)(ws + (size_t)33554432 + 524288);   // 512*512*4

  k_transpose<<<dim3(EMBED / 32, HIDDEN / 32), dim3(32, 8), 0, stream>>>(Wih, WtIh, HIDDEN, EMBED);
  k_transpose<<<dim3(HIDDEN / 32, HIDDEN / 32), dim3(32, 8), 0, stream>>>(Whh, WtHh, HIDDEN, HIDDEN);
  k_xproj<<<BATCH * SEQ / 16, 512, 0, stream>>>(x, emb, WtIh, bih, bhh, buf);
  k_rnn<<<BATCH, 512, 0, stream>>>(h0, WtHh, buf, out);
  k_logits<<<dim3(VOCAB / 128, BATCH * SEQ / 128), 256, 0, stream>>>(buf, Wout, bout, out);
}